// Round 12
// baseline (5523.816 us; speedup 1.0000x reference)
//
#include <hip/hip_runtime.h>

// ---------------------------------------------------------------------------
// Persistent LSTM, bf16 MFMA, R4 sync + coalesced h transport + W-in-LDS.
// T=1024 B=64 C=256 H=512, 2 layers, fp32 in/out.
//  - 256 blocks x 256 threads, 1 block/CU; blocks 0..127 = layer0 (step t),
//    128..255 = layer1 (step t-1); R4 flag barrier (block flags -> block0
//    wave-scan -> gen lines -> tid0 poll) -- unchanged (best measured).
//  - h transport (R11, proven): [producer][batch] u64 layout; producer packs
//    4 cols/row into one u64 (3 shuffles, 1 store per 4 lanes, 128B-contig
//    per wave -> full-line writes; WRITE_SIZE 796->403 MB). Consumers read
//    2x 8B per fragment (128B-contiguous chunks per instruction).
//  - NEW 1: packed W lives in static LDS (24/32 KB per block, staged once).
//    R4..R11 pinned W in VGPRs, but layer1 needs 128 afr regs + 128 W regs:
//    VGPR_Count=156 proves the pin never held -- the compiler spilled and
//    reloaded 32 W frags EVERY tick inside the MFMA chain. ds_read_b128 is
//    conflict-free lane-contiguous and compiler-pipelined against MFMAs.
//  - NEW 2: out stores packed to float4 by lane jj=0 (cols consecutive) ->
//    4x fewer transactions, kills most of the out partial-line RMW fetch
//    (the FETCH_SIZE 808 MB residue).
//  - mfma_f32_16x16x32_bf16: A[m=lane&15][k=quad*8+j], B(N,K)[n=lane&15][k=quad*8+j],
//    D[m=quad*4+reg][n=lane&15]  (guide-verified mapping, m90/m97 convention)
// ---------------------------------------------------------------------------

#define TT 1024
#define BB 64
#define CC 256
#define HH 512
#define Y_ELEMS (TT * BB * HH)
#define S_ELEMS (BB * HH)

typedef __attribute__((ext_vector_type(8))) short bf16x8;
typedef __attribute__((ext_vector_type(4))) float f32x4;
typedef unsigned int u32;
typedef unsigned short u16;
typedef unsigned long long u64;

// ---- ws layout (bytes) ----
#define WS_BAR 0           // 256 slots * 128B
#define WS_GEN 32768       // 4 gen lines * 128B
#define WS_BSUM0 36864     // 2048 f32
#define WS_BSUM1 45056     // 2048 f32
#define WS_H0 53248        // 2 * 65536 B  (h0 ping-pong, [128][64] u64)
#define WS_H1 184320       // 2 * 65536 B  (h1 ping-pong, [128][64] u64)
#define WS_WPK0 315392     // 128*24*64*8 bf16  (layer0 packed W)
#define WS_WPK1 3461120    // 128*32*64*8 bf16  (layer1 packed W)
// end 7655424 (~7.66 MB)

__device__ __forceinline__ u16 f2b_rne(float f) {
    u32 u = __float_as_uint(f);
    return (u16)((u + 0x7FFFu + ((u >> 16) & 1u)) >> 16);
}
__device__ __forceinline__ u16 f2b_fast(float f) {  // round-half-up, 2 ops
    return (u16)((__float_as_uint(f) + 0x8000u) >> 16);
}
__device__ __forceinline__ float sigf(float z) { return 1.0f / (1.0f + __expf(-z)); }
__device__ __forceinline__ float tanh_f(float z) { return 2.0f / (1.0f + __expf(-2.0f * z)) - 1.0f; }

__device__ __forceinline__ bf16x8 pack8(float4 a, float4 b) {
    union { u16 u[8]; bf16x8 v; } r;
    r.u[0] = f2b_fast(a.x); r.u[1] = f2b_fast(a.y); r.u[2] = f2b_fast(a.z); r.u[3] = f2b_fast(a.w);
    r.u[4] = f2b_fast(b.x); r.u[5] = f2b_fast(b.y); r.u[6] = f2b_fast(b.z); r.u[7] = f2b_fast(b.w);
    return r.v;
}

__device__ __forceinline__ u32 ld_u32_sc(const u32* p) {
    return __hip_atomic_load(p, __ATOMIC_RELAXED, __HIP_MEMORY_SCOPE_AGENT);
}
__device__ __forceinline__ void st_u32_sc(u32* p, u32 v) {
    __hip_atomic_store(p, v, __ATOMIC_RELAXED, __HIP_MEMORY_SCOPE_AGENT);
}

// ---- init: zero flags/gens, bsum = bih+bhh, h slot0 <- bf16(h_init), [p][b] layout ----
// element (b,col) -> u16 index (col>>2)*256 + b*4 + (col&3)
__global__ void k_init(const float* __restrict__ bih0, const float* __restrict__ bhh0,
                       const float* __restrict__ bih1, const float* __restrict__ bhh1,
                       const float* __restrict__ h00, const float* __restrict__ h01,
                       unsigned char* __restrict__ ws) {
    u32* bar = (u32*)(ws + WS_BAR);
    float* bs0 = (float*)(ws + WS_BSUM0);
    float* bs1 = (float*)(ws + WS_BSUM1);
    u16* h0 = (u16*)(ws + WS_H0);
    u16* h1 = (u16*)(ws + WS_H1);
    int t = blockIdx.x * 256 + threadIdx.x;  // 32768 threads
    if (t < 8448) bar[t] = 0u;               // slots + gen region
    if (t < 2048) { bs0[t] = bih0[t] + bhh0[t]; bs1[t] = bih1[t] + bhh1[t]; }
    if (t < S_ELEMS) {
        int b = t >> 9, col = t & 511;
        int no = ((col >> 2) << 8) + (b << 2) + (col & 3);
        h0[no] = f2b_rne(h00[t]);
        h1[no] = f2b_rne(h01[t]);
    }
}

// ---- weight pack: fp32 [4H,K] -> bf16 B-frag order wpk[bidL][kt][lane][8] ----
// rows permuted: n-index (lane&15) = gg*4+jj  <->  W row = gg*512 + bidL*4 + jj
__global__ void k_wprep(const float* __restrict__ Wih0, const float* __restrict__ Whh0,
                        const float* __restrict__ Wih1, const float* __restrict__ Whh1,
                        unsigned char* __restrict__ ws) {
    u16* wpk0 = (u16*)(ws + WS_WPK0);
    u16* wpk1 = (u16*)(ws + WS_WPK1);
    int u = blockIdx.x * 256 + threadIdx.x;  // 458752 threads
    const float* s;
    u16* d;
    if (u < 128 * 24 * 64) {  // layer0: 8 x-tiles (K=256) + 16 h-tiles (K=512)
        int bidL = u / (24 * 64);
        int kt = (u >> 6) % 24;
        int lane = u & 63;
        int n = lane & 15, quad = lane >> 4;
        int row = (n >> 2) * 512 + bidL * 4 + (n & 3);
        int k = kt * 32 + quad * 8;
        s = (k < 256) ? (Wih0 + (size_t)row * 256 + k) : (Whh0 + (size_t)row * 512 + (k - 256));
        d = wpk0 + (size_t)((bidL * 24 + kt) * 64 + lane) * 8;
    } else {  // layer1: 16 y0-tiles + 16 h1-tiles (K=1024)
        int v = u - 128 * 24 * 64;
        int bidL = v / (32 * 64);
        int kt = (v >> 6) % 32;
        int lane = v & 63;
        int n = lane & 15, quad = lane >> 4;
        int row = (n >> 2) * 512 + bidL * 4 + (n & 3);
        int k = kt * 32 + quad * 8;
        s = (k < 512) ? (Wih1 + (size_t)row * 512 + k) : (Whh1 + (size_t)row * 512 + (k - 512));
        d = wpk1 + (size_t)((bidL * 32 + kt) * 64 + lane) * 8;
    }
    #pragma unroll
    for (int i = 0; i < 8; ++i) d[i] = f2b_rne(s[i]);
}

// ---- the persistent tick loop, templated on layer ----
template <int LAYER>
__device__ void run_ticks(const float* __restrict__ x, const float* __restrict__ c0,
                          float* __restrict__ out, unsigned char* __restrict__ ws,
                          int bidL, u16* wlds) {
    constexpr int NKT = (LAYER == 0) ? 24 : 32;
    u32* slots = (u32*)(ws + WS_BAR);
    u32* gen = (u32*)(ws + WS_GEN);
    const float* bs = (const float*)(ws + (LAYER == 0 ? WS_BSUM0 : WS_BSUM1));
    u16* h0base = (u16*)(ws + WS_H0);    // 2 slots of S_ELEMS u16 ([128][64] u64)
    u16* h1base = (u16*)(ws + WS_H1);
    const u16* wpk = (const u16*)(ws + (LAYER == 0 ? WS_WPK0 : WS_WPK1));

    const int tid = threadIdx.x, lane = tid & 63, wave = tid >> 6;
    const int r16 = lane & 15, quad = lane >> 4, q8 = quad * 8;
    const int gg = r16 >> 2, jj = r16 & 3;
    const int b0 = wave * 16;
    const int col = bidL * 4 + jj;            // h column this lane finalizes
    const int myb = b0 + quad * 4 + gg;       // batch this lane finalizes
    const int sl0 = (quad << 4) | (0 << 2) | jj;
    const int sl1 = (quad << 4) | (1 << 2) | jj;
    const int sl2 = (quad << 4) | (2 << 2) | jj;
    const int sl3 = (quad << 4) | (3 << 2) | jj;
    const int baseln = (quad << 4) | (gg << 2);   // lane jj=0 of my (quad,gg) group

    // per-lane consumer chunk base offset (bytes): quad*1024 + rb*8
    const size_t cbase = (size_t)quad * 1024 + (size_t)(b0 + r16) * 8;

    // ---- stage this block's packed W tile into LDS (once) ----
    {
        const u16* src = wpk + (size_t)(bidL * NKT * 64) * 8;
        for (int ofs = tid * 8; ofs < NKT * 512; ofs += 256 * 8)
            *(f32x4*)(wlds + ofs) = *(const f32x4*)(src + ofs);
        __syncthreads();
    }
    const u16* wl = wlds + (size_t)lane * 8;      // this lane's fragment base

    // biases (hoisted), c state in register for the whole run
    const float bi = bs[0 * HH + col], bf_ = bs[1 * HH + col];
    const float bg = bs[2 * HH + col], bo = bs[3 * HH + col];
    float c = c0[myb * HH + col];

    // layer0: x prefetch registers (t=0 issued before the loop)
    float4 xf0[8], xf1[8];
    if (LAYER == 0) {
        const float* xp = x + (size_t)(b0 + r16) * CC + q8;
        #pragma unroll
        for (int kt = 0; kt < 8; ++kt) {
            xf0[kt] = *(const float4*)(xp + kt * 32);
            xf1[kt] = *(const float4*)(xp + kt * 32 + 4);
        }
    }

    for (int i = 0; i <= TT; ++i) {
        const bool active = (LAYER == 0) ? (i < TT) : (i >= 1);
        const int t = (LAYER == 0) ? i : i - 1;
        float h = 0.f;
        if (active) {
            f32x4 a0 = {0.f,0.f,0.f,0.f}, a1 = {0.f,0.f,0.f,0.f};
            f32x4 a2 = {0.f,0.f,0.f,0.f}, a3 = {0.f,0.f,0.f,0.f};
            if (LAYER == 0) {
                // 16 frags = 32x 8B loads, one LLC round
                u64 alo[16], ahi[16];
                {
                    const char* hb = (const char*)(h0base + (size_t)(t & 1) * S_ELEMS) + cbase;
                    #pragma unroll
                    for (int kt = 0; kt < 16; ++kt) {
                        const char* pk = hb + kt * 4096;
                        asm volatile("global_load_dwordx2 %0, %1, off sc0 sc1"
                                     : "=&v"(alo[kt]) : "v"(pk) : "memory");
                        asm volatile("global_load_dwordx2 %0, %1, off offset:512 sc0 sc1"
                                     : "=&v"(ahi[kt]) : "v"(pk) : "memory");
                    }
                }
                // x projection (registers + LDS W) overlaps the h-load flight
                #pragma unroll
                for (int kt = 0; kt < 8; ++kt) {
                    bf16x8 a = pack8(xf0[kt], xf1[kt]);
                    bf16x8 wv = *(const bf16x8*)(wl + (size_t)kt * 512);
                    f32x4& dst = (kt & 2) ? ((kt & 1) ? a3 : a2) : ((kt & 1) ? a1 : a0);
                    dst = __builtin_amdgcn_mfma_f32_16x16x32_bf16(a, wv, dst, 0, 0, 0);
                }
                asm volatile("s_waitcnt vmcnt(0)" ::: "memory");
                __builtin_amdgcn_sched_barrier(0);
                #pragma unroll
                for (int kt = 0; kt < 16; ++kt) {
                    union { u64 q[2]; bf16x8 v; } fa;
                    fa.q[0] = alo[kt]; fa.q[1] = ahi[kt];
                    bf16x8 wv = *(const bf16x8*)(wl + (size_t)(8 + kt) * 512);
                    f32x4& dst = (kt & 2) ? ((kt & 1) ? a3 : a2) : ((kt & 1) ? a1 : a0);
                    dst = __builtin_amdgcn_mfma_f32_16x16x32_bf16(fa.v, wv, dst, 0, 0, 0);
                }
            } else {
                // y0[t] = h0 slot (t+1)&1; h1 prev = slot t&1
                u64 plo[16], phi[16], qlo[16], qhi[16];
                {
                    const char* ha = (const char*)(h0base + (size_t)((t + 1) & 1) * S_ELEMS) + cbase;
                    const char* hb = (const char*)(h1base + (size_t)(t & 1) * S_ELEMS) + cbase;
                    #pragma unroll
                    for (int kt = 0; kt < 16; ++kt) {     // h1 first
                        const char* pk = hb + kt * 4096;
                        asm volatile("global_load_dwordx2 %0, %1, off sc0 sc1"
                                     : "=&v"(qlo[kt]) : "v"(pk) : "memory");
                        asm volatile("global_load_dwordx2 %0, %1, off offset:512 sc0 sc1"
                                     : "=&v"(qhi[kt]) : "v"(pk) : "memory");
                    }
                    #pragma unroll
                    for (int kt = 0; kt < 16; ++kt) {
                        const char* pk = ha + kt * 4096;
                        asm volatile("global_load_dwordx2 %0, %1, off sc0 sc1"
                                     : "=&v"(plo[kt]) : "v"(pk) : "memory");
                        asm volatile("global_load_dwordx2 %0, %1, off offset:512 sc0 sc1"
                                     : "=&v"(phi[kt]) : "v"(pk) : "memory");
                    }
                }
                asm volatile("s_waitcnt vmcnt(0)" ::: "memory");
                __builtin_amdgcn_sched_barrier(0);
                #pragma unroll
                for (int kt = 0; kt < 32; ++kt) {
                    union { u64 q[2]; bf16x8 v; } fa;
                    if (kt < 16) { fa.q[0] = plo[kt]; fa.q[1] = phi[kt]; }
                    else         { fa.q[0] = qlo[kt - 16]; fa.q[1] = qhi[kt - 16]; }
                    bf16x8 wv = *(const bf16x8*)(wl + (size_t)kt * 512);
                    f32x4& dst = (kt & 2) ? ((kt & 1) ? a3 : a2) : ((kt & 1) ? a1 : a0);
                    dst = __builtin_amdgcn_mfma_f32_16x16x32_bf16(fa.v, wv, dst, 0, 0, 0);
                }
            }
            f32x4 acc = (a0 + a1) + (a2 + a3);

            // gates for (myb, col): lanes sharing (quad,jj), gg = gate
            float gi = 0.f, gf = 0.f, gc = 0.f, go = 0.f;
            #pragma unroll
            for (int r = 0; r < 4; ++r) {
                float v0 = __shfl(acc[r], sl0, 64);
                float v1 = __shfl(acc[r], sl1, 64);
                float v2 = __shfl(acc[r], sl2, 64);
                float v3 = __shfl(acc[r], sl3, 64);
                if (r == gg) { gi = v0; gf = v1; gc = v2; go = v3; }
            }
            gi = sigf(gi + bi);
            gf = sigf(gf + bf_);
            gc = tanh_f(gc + bg);
            go = sigf(go + bo);
            c = gf * c + gi * gc;
            h = go * tanh_f(c);

            // ---- coalesced h store: pack 4 cols of row myb into one u64 ----
            u32 w0 = f2b_rne(h);
            u32 w1 = (u32)__shfl((int)w0, baseln + 1, 64);
            u32 w2 = (u32)__shfl((int)w0, baseln + 2, 64);
            u32 w3 = (u32)__shfl((int)w0, baseln + 3, 64);
            if (jj == 0) {
                u64 pkd = (u64)(w0 | (w1 << 16)) | ((u64)(w2 | (w3 << 16)) << 32);
                u64* hw = (u64*)((LAYER == 0 ? h0base : h1base)
                                 + (size_t)((t + 1) & 1) * S_ELEMS)
                          + (size_t)bidL * 64 + myb;
                __hip_atomic_store(hw, pkd, __ATOMIC_RELAXED, __HIP_MEMORY_SCOPE_AGENT);
            }
        }
        // ---- barrier arrival: drain h store, then raise flag ----
        if (i < TT) {
            asm volatile("s_waitcnt vmcnt(0)" ::: "memory");
            __syncthreads();   // all waves of this block drained
            if (tid == 0)
                st_u32_sc(&slots[(u32)blockIdx.x * 32], (u32)(i + 1));
        }
        // ---- shadow work while flags propagate / peers finish ----
        if (active) {
            if (LAYER == 1) {
                // packed out store: lane jj=0 writes float4 (cols bidL*4..+3)
                float o1 = __shfl(h, baseln + 1, 64);
                float o2 = __shfl(h, baseln + 2, 64);
                float o3 = __shfl(h, baseln + 3, 64);
                if (jj == 0) {
                    float4 ov = { h, o1, o2, o3 };
                    *(float4*)(out + (size_t)t * S_ELEMS + (size_t)myb * HH + bidL * 4) = ov;
                }
            }
            if (t == TT - 1) {
                float* fin = out + Y_ELEMS + (LAYER == 0 ? 0 : 2) * S_ELEMS;
                fin[myb * HH + col] = h;
                fin[S_ELEMS + myb * HH + col] = c;
            }
        }
        if (LAYER == 0 && i + 1 < TT) {      // prefetch x[t+1] into registers
            const float* xp = x + ((size_t)(i + 1) * BB + b0 + r16) * CC + q8;
            #pragma unroll
            for (int kt = 0; kt < 8; ++kt) {
                xf0[kt] = *(const float4*)(xp + kt * 32);
                xf1[kt] = *(const float4*)(xp + kt * 32 + 4);
            }
        }
        // ---- barrier completion: aggregator (block 0) or gen-poll (others) ----
        if (i < TT) {
            const u32 tgt = (u32)(i + 1);
            if (blockIdx.x == 0) {
                if (tid < 64) {  // wave 0 scans all 256 slots, 4 per lane
                    const u32* p0 = slots + ((u32)tid * 4 + 0) * 32;
                    const u32* p1 = slots + ((u32)tid * 4 + 1) * 32;
                    const u32* p2 = slots + ((u32)tid * 4 + 2) * 32;
                    const u32* p3 = slots + ((u32)tid * 4 + 3) * 32;
                    u32 m;
                    do {
                        u32 va = ld_u32_sc(p0);
                        u32 vb = ld_u32_sc(p1);
                        u32 vc = ld_u32_sc(p2);
                        u32 vd = ld_u32_sc(p3);
                        m = min(min(va, vb), min(vc, vd));
                    } while (m < tgt);
                }
                __syncthreads();
                if (tid == 0) {
                    #pragma unroll
                    for (int k2 = 0; k2 < 4; ++k2) st_u32_sc(gen + k2 * 32, tgt);
                }
            } else {
                if (tid == 0) {
                    const u32* gp = gen + ((u32)blockIdx.x & 3) * 32;
                    while (ld_u32_sc(gp) < tgt) { }
                }
                __syncthreads();
            }
        }
    }
}

__global__ __launch_bounds__(256) __attribute__((amdgpu_waves_per_eu(1, 1)))
void k_lstm(const float* __restrict__ x,
            const float* __restrict__ c00,
            const float* __restrict__ c01,
            float* __restrict__ out,
            unsigned char* __restrict__ ws) {
    __shared__ __align__(16) u16 wlds[16384];   // 32 KB: packed W tile
    const int bid = blockIdx.x;
    if (bid < 128) run_ticks<0>(x, c00, out, ws, bid, wlds);
    else           run_ticks<1>(x, c01, out, ws, bid - 128, wlds);
}

extern "C" void kernel_launch(void* const* d_in, const int* in_sizes, int n_in,
                              void* d_out, int out_size, void* d_ws, size_t ws_size,
                              hipStream_t stream) {
    const float* x    = (const float*)d_in[0];
    const float* h0_0 = (const float*)d_in[1];
    const float* c0_0 = (const float*)d_in[2];
    const float* h0_1 = (const float*)d_in[3];
    const float* c0_1 = (const float*)d_in[4];
    const float* Wih0 = (const float*)d_in[5];
    const float* Whh0 = (const float*)d_in[6];
    const float* bih0 = (const float*)d_in[7];
    const float* bhh0 = (const float*)d_in[8];
    const float* Wih1 = (const float*)d_in[9];
    const float* Whh1 = (const float*)d_in[10];
    const float* bih1 = (const float*)d_in[11];
    const float* bhh1 = (const float*)d_in[12];
    float* out = (float*)d_out;
    unsigned char* ws = (unsigned char*)d_ws;

    k_init<<<128, 256, 0, stream>>>(bih0, bhh0, bih1, bhh1, h0_0, h0_1, ws);
    k_wprep<<<1792, 256, 0, stream>>>(Wih0, Whh0, Wih1, Whh1, ws);
    k_lstm<<<256, 256, 0, stream>>>(x, c0_0, c0_1, out, ws);
}

// Round 13
// 4984.343 us; speedup vs baseline: 1.1082x; 1.1082x over previous
//
#include <hip/hip_runtime.h>

// ---------------------------------------------------------------------------
// Persistent weight-stationary LSTM, bf16 MFMA, counter-join sync (2-hop).
// T=1024 B=64 C=256 H=512, 2 layers, fp32 in/out.
//  - 256 blocks x 256 threads, 1 block/CU; blocks 0..127 = layer0 (step t),
//    128..255 = layer1 (step t-1); one join per tick.
//  - BARRIER (new): 8 spread counter lines; tid0 of each block does ONE
//    relaxed agent fetch-add to line (bid&7) after drain; workers' tid0
//    polls the 8 lines (8 loads in flight) for all >= 32*(i+1).
//    2 hops (add-flight + poll-observe) vs R4's 3 (flag->block0 scan->gen->
//    poll). No aggregator. Poll traffic ~2K loads/round (R4-safe).
//    R0's contended-add slowness was acq_rel + L2 wbinv (proven R2), not RMW.
//  - h transport (R11, proven): [producer][batch] u64 layout; producer packs
//    4 cols/row into one u64 (3 shuffles) -> full-line wave stores
//    (WRITE_SIZE 796->403 MB); consumers read 2x 8B per fragment,
//    128B-contiguous per instruction. Weights: R11 VGPR path (R12's W-in-LDS
//    regressed: serial lgkmcnt in MFMA chain at 1 wave/SIMD).
//  - Layer1 split wait: h1 loads -> h0 loads -> vmcnt(32) -> 16 h1-MFMAs
//    overlap h0 flight -> vmcnt(0) -> 16 h0-MFMAs.
//  - out: float4 packed store by lane jj=0 (shadow work).
//  - mfma_f32_16x16x32_bf16: A[m=lane&15][k=quad*8+j], B(N,K)[n=lane&15][k=quad*8+j],
//    D[m=quad*4+reg][n=lane&15]  (guide-verified mapping, m90/m97 convention)
// ---------------------------------------------------------------------------

#define TT 1024
#define BB 64
#define CC 256
#define HH 512
#define Y_ELEMS (TT * BB * HH)
#define S_ELEMS (BB * HH)

typedef __attribute__((ext_vector_type(8))) short bf16x8;
typedef __attribute__((ext_vector_type(4))) float f32x4;
typedef unsigned int u32;
typedef unsigned short u16;
typedef unsigned long long u64;

// ---- ws layout (bytes) ----
#define WS_BAR 0           // (legacy flag region, unused)
#define WS_CNT 32768       // 8 counter lines * 128B
#define WS_BSUM0 36864     // 2048 f32
#define WS_BSUM1 45056     // 2048 f32
#define WS_H0 53248        // 2 * 65536 B  (h0 ping-pong, [128][64] u64)
#define WS_H1 184320       // 2 * 65536 B  (h1 ping-pong, [128][64] u64)
#define WS_WPK0 315392     // 128*24*64*8 bf16  (layer0 packed W)
#define WS_WPK1 3461120    // 128*32*64*8 bf16  (layer1 packed W)
// end 7655424 (~7.66 MB)

__device__ __forceinline__ u16 f2b_rne(float f) {
    u32 u = __float_as_uint(f);
    return (u16)((u + 0x7FFFu + ((u >> 16) & 1u)) >> 16);
}
__device__ __forceinline__ u16 f2b_fast(float f) {  // round-half-up, 2 ops
    return (u16)((__float_as_uint(f) + 0x8000u) >> 16);
}
__device__ __forceinline__ float sigf(float z) { return 1.0f / (1.0f + __expf(-z)); }
__device__ __forceinline__ float tanh_f(float z) { return 2.0f / (1.0f + __expf(-2.0f * z)) - 1.0f; }

__device__ __forceinline__ bf16x8 pack8(float4 a, float4 b) {
    union { u16 u[8]; bf16x8 v; } r;
    r.u[0] = f2b_fast(a.x); r.u[1] = f2b_fast(a.y); r.u[2] = f2b_fast(a.z); r.u[3] = f2b_fast(a.w);
    r.u[4] = f2b_fast(b.x); r.u[5] = f2b_fast(b.y); r.u[6] = f2b_fast(b.z); r.u[7] = f2b_fast(b.w);
    return r.v;
}

__device__ __forceinline__ u32 ld_u32_sc(const u32* p) {
    return __hip_atomic_load(p, __ATOMIC_RELAXED, __HIP_MEMORY_SCOPE_AGENT);
}
__device__ __forceinline__ void add_u32_sc(u32* p, u32 v) {
    (void)__hip_atomic_fetch_add(p, v, __ATOMIC_RELAXED, __HIP_MEMORY_SCOPE_AGENT);
}

// ---- init: zero counters, bsum = bih+bhh, h slot0 <- bf16(h_init), [p][b] layout ----
// element (b,col) -> u16 index (col>>2)*256 + b*4 + (col&3)
__global__ void k_init(const float* __restrict__ bih0, const float* __restrict__ bhh0,
                       const float* __restrict__ bih1, const float* __restrict__ bhh1,
                       const float* __restrict__ h00, const float* __restrict__ h01,
                       unsigned char* __restrict__ ws) {
    u32* bar = (u32*)(ws + WS_BAR);
    float* bs0 = (float*)(ws + WS_BSUM0);
    float* bs1 = (float*)(ws + WS_BSUM1);
    u16* h0 = (u16*)(ws + WS_H0);
    u16* h1 = (u16*)(ws + WS_H1);
    int t = blockIdx.x * 256 + threadIdx.x;  // 32768 threads
    if (t < 8448) bar[t] = 0u;               // legacy flags + counter lines
    if (t < 2048) { bs0[t] = bih0[t] + bhh0[t]; bs1[t] = bih1[t] + bhh1[t]; }
    if (t < S_ELEMS) {
        int b = t >> 9, col = t & 511;
        int no = ((col >> 2) << 8) + (b << 2) + (col & 3);
        h0[no] = f2b_rne(h00[t]);
        h1[no] = f2b_rne(h01[t]);
    }
}

// ---- weight pack: fp32 [4H,K] -> bf16 B-frag order wpk[bidL][kt][lane][8] ----
// rows permuted: n-index (lane&15) = gg*4+jj  <->  W row = gg*512 + bidL*4 + jj
__global__ void k_wprep(const float* __restrict__ Wih0, const float* __restrict__ Whh0,
                        const float* __restrict__ Wih1, const float* __restrict__ Whh1,
                        unsigned char* __restrict__ ws) {
    u16* wpk0 = (u16*)(ws + WS_WPK0);
    u16* wpk1 = (u16*)(ws + WS_WPK1);
    int u = blockIdx.x * 256 + threadIdx.x;  // 458752 threads
    const float* s;
    u16* d;
    if (u < 128 * 24 * 64) {  // layer0: 8 x-tiles (K=256) + 16 h-tiles (K=512)
        int bidL = u / (24 * 64);
        int kt = (u >> 6) % 24;
        int lane = u & 63;
        int n = lane & 15, quad = lane >> 4;
        int row = (n >> 2) * 512 + bidL * 4 + (n & 3);
        int k = kt * 32 + quad * 8;
        s = (k < 256) ? (Wih0 + (size_t)row * 256 + k) : (Whh0 + (size_t)row * 512 + (k - 256));
        d = wpk0 + (size_t)((bidL * 24 + kt) * 64 + lane) * 8;
    } else {  // layer1: 16 y0-tiles + 16 h1-tiles (K=1024)
        int v = u - 128 * 24 * 64;
        int bidL = v / (32 * 64);
        int kt = (v >> 6) % 32;
        int lane = v & 63;
        int n = lane & 15, quad = lane >> 4;
        int row = (n >> 2) * 512 + bidL * 4 + (n & 3);
        int k = kt * 32 + quad * 8;
        s = (k < 512) ? (Wih1 + (size_t)row * 512 + k) : (Whh1 + (size_t)row * 512 + (k - 512));
        d = wpk1 + (size_t)((bidL * 32 + kt) * 64 + lane) * 8;
    }
    #pragma unroll
    for (int i = 0; i < 8; ++i) d[i] = f2b_rne(s[i]);
}

// ---- the persistent tick loop, templated on layer ----
template <int LAYER>
__device__ void run_ticks(const float* __restrict__ x, const float* __restrict__ c0,
                          float* __restrict__ out, unsigned char* __restrict__ ws, int bidL) {
    constexpr int NKT = (LAYER == 0) ? 24 : 32;
    u32* cnt = (u32*)(ws + WS_CNT);      // 8 lines, stride 32 u32
    const float* bs = (const float*)(ws + (LAYER == 0 ? WS_BSUM0 : WS_BSUM1));
    u16* h0base = (u16*)(ws + WS_H0);    // 2 slots of S_ELEMS u16 ([128][64] u64)
    u16* h1base = (u16*)(ws + WS_H1);
    const u16* wpk = (const u16*)(ws + (LAYER == 0 ? WS_WPK0 : WS_WPK1));

    const int tid = threadIdx.x, lane = tid & 63, wave = tid >> 6;
    const int r16 = lane & 15, quad = lane >> 4, q8 = quad * 8;
    const int gg = r16 >> 2, jj = r16 & 3;
    const int b0 = wave * 16;
    const int col = bidL * 4 + jj;            // h column this lane finalizes
    const int myb = b0 + quad * 4 + gg;       // batch this lane finalizes
    const int sl0 = (quad << 4) | (0 << 2) | jj;
    const int sl1 = (quad << 4) | (1 << 2) | jj;
    const int sl2 = (quad << 4) | (2 << 2) | jj;
    const int sl3 = (quad << 4) | (3 << 2) | jj;
    const int baseln = (quad << 4) | (gg << 2);   // lane jj=0 of my (quad,gg) group

    // per-lane consumer chunk base offset (bytes): quad*1024 + rb*8
    const size_t cbase = (size_t)quad * 1024 + (size_t)(b0 + r16) * 8;

    u32* mycnt = cnt + ((u32)blockIdx.x & 7) * 32;

    // biases (hoisted), c state in register for the whole run
    const float bi = bs[0 * HH + col], bf_ = bs[1 * HH + col];
    const float bg = bs[2 * HH + col], bo = bs[3 * HH + col];
    float c = c0[myb * HH + col];

    // weight fragments: load once, pin (R11-identical; R12's LDS path regressed)
    f32x4 wf[NKT];
    {
        const u16* wp = wpk + (size_t)(bidL * NKT * 64 + lane) * 8;
        #pragma unroll
        for (int kt = 0; kt < NKT; ++kt) wf[kt] = *(const f32x4*)(wp + (size_t)kt * 64 * 8);
        #pragma unroll
        for (int kt = 0; kt < NKT; ++kt) asm volatile("" : "+v"(wf[kt]));
    }

    // layer0: x prefetch registers (t=0 issued before the loop)
    float4 xf0[8], xf1[8];
    if (LAYER == 0) {
        const float* xp = x + (size_t)(b0 + r16) * CC + q8;
        #pragma unroll
        for (int kt = 0; kt < 8; ++kt) {
            xf0[kt] = *(const float4*)(xp + kt * 32);
            xf1[kt] = *(const float4*)(xp + kt * 32 + 4);
        }
    }

    for (int i = 0; i <= TT; ++i) {
        const bool active = (LAYER == 0) ? (i < TT) : (i >= 1);
        const int t = (LAYER == 0) ? i : i - 1;
        float h = 0.f;
        if (active) {
            f32x4 a0 = {0.f,0.f,0.f,0.f}, a1 = {0.f,0.f,0.f,0.f};
            f32x4 a2 = {0.f,0.f,0.f,0.f}, a3 = {0.f,0.f,0.f,0.f};
            if (LAYER == 0) {
                // 16 frags = 32x 8B loads, one LLC round
                u64 alo[16], ahi[16];
                {
                    const char* hb = (const char*)(h0base + (size_t)(t & 1) * S_ELEMS) + cbase;
                    #pragma unroll
                    for (int kt = 0; kt < 16; ++kt) {
                        const char* pk = hb + kt * 4096;
                        asm volatile("global_load_dwordx2 %0, %1, off sc0 sc1"
                                     : "=&v"(alo[kt]) : "v"(pk) : "memory");
                        asm volatile("global_load_dwordx2 %0, %1, off offset:512 sc0 sc1"
                                     : "=&v"(ahi[kt]) : "v"(pk) : "memory");
                    }
                }
                // x projection from prefetched registers overlaps the h-load flight
                #pragma unroll
                for (int kt = 0; kt < 8; ++kt) {
                    bf16x8 a = pack8(xf0[kt], xf1[kt]);
                    bf16x8 wv = __builtin_bit_cast(bf16x8, wf[kt]);
                    f32x4& dst = (kt & 2) ? ((kt & 1) ? a3 : a2) : ((kt & 1) ? a1 : a0);
                    dst = __builtin_amdgcn_mfma_f32_16x16x32_bf16(a, wv, dst, 0, 0, 0);
                }
                asm volatile("s_waitcnt vmcnt(0)" ::: "memory");
                __builtin_amdgcn_sched_barrier(0);
                #pragma unroll
                for (int kt = 0; kt < 16; ++kt) {
                    union { u64 q[2]; bf16x8 v; } fa;
                    fa.q[0] = alo[kt]; fa.q[1] = ahi[kt];
                    bf16x8 wv = __builtin_bit_cast(bf16x8, wf[8 + kt]);
                    f32x4& dst = (kt & 2) ? ((kt & 1) ? a3 : a2) : ((kt & 1) ? a1 : a0);
                    dst = __builtin_amdgcn_mfma_f32_16x16x32_bf16(fa.v, wv, dst, 0, 0, 0);
                }
            } else {
                // y0[t] = h0 slot (t+1)&1; h1 prev = slot t&1
                u64 plo[16], phi[16], qlo[16], qhi[16];
                {
                    const char* ha = (const char*)(h0base + (size_t)((t + 1) & 1) * S_ELEMS) + cbase;
                    const char* hb = (const char*)(h1base + (size_t)(t & 1) * S_ELEMS) + cbase;
                    #pragma unroll
                    for (int kt = 0; kt < 16; ++kt) {     // h1 first
                        const char* pk = hb + kt * 4096;
                        asm volatile("global_load_dwordx2 %0, %1, off sc0 sc1"
                                     : "=&v"(qlo[kt]) : "v"(pk) : "memory");
                        asm volatile("global_load_dwordx2 %0, %1, off offset:512 sc0 sc1"
                                     : "=&v"(qhi[kt]) : "v"(pk) : "memory");
                    }
                    #pragma unroll
                    for (int kt = 0; kt < 16; ++kt) {     // h0 second
                        const char* pk = ha + kt * 4096;
                        asm volatile("global_load_dwordx2 %0, %1, off sc0 sc1"
                                     : "=&v"(plo[kt]) : "v"(pk) : "memory");
                        asm volatile("global_load_dwordx2 %0, %1, off offset:512 sc0 sc1"
                                     : "=&v"(phi[kt]) : "v"(pk) : "memory");
                    }
                }
                // h1 fragments (first 32 loads) ready when <=32 outstanding
                asm volatile("s_waitcnt vmcnt(32)" ::: "memory");
                __builtin_amdgcn_sched_barrier(0);
                #pragma unroll
                for (int kt = 16; kt < 32; ++kt) {   // h1-MFMAs overlap h0 flight
                    union { u64 q[2]; bf16x8 v; } fa;
                    fa.q[0] = qlo[kt - 16]; fa.q[1] = qhi[kt - 16];
                    bf16x8 wv = __builtin_bit_cast(bf16x8, wf[kt]);
                    f32x4& dst = (kt & 2) ? ((kt & 1) ? a3 : a2) : ((kt & 1) ? a1 : a0);
                    dst = __builtin_amdgcn_mfma_f32_16x16x32_bf16(fa.v, wv, dst, 0, 0, 0);
                }
                asm volatile("s_waitcnt vmcnt(0)" ::: "memory");
                __builtin_amdgcn_sched_barrier(0);
                #pragma unroll
                for (int kt = 0; kt < 16; ++kt) {
                    union { u64 q[2]; bf16x8 v; } fa;
                    fa.q[0] = plo[kt]; fa.q[1] = phi[kt];
                    bf16x8 wv = __builtin_bit_cast(bf16x8, wf[kt]);
                    f32x4& dst = (kt & 2) ? ((kt & 1) ? a3 : a2) : ((kt & 1) ? a1 : a0);
                    dst = __builtin_amdgcn_mfma_f32_16x16x32_bf16(fa.v, wv, dst, 0, 0, 0);
                }
            }
            f32x4 acc = (a0 + a1) + (a2 + a3);

            // gates for (myb, col): lanes sharing (quad,jj), gg = gate
            float gi = 0.f, gf = 0.f, gc = 0.f, go = 0.f;
            #pragma unroll
            for (int r = 0; r < 4; ++r) {
                float v0 = __shfl(acc[r], sl0, 64);
                float v1 = __shfl(acc[r], sl1, 64);
                float v2 = __shfl(acc[r], sl2, 64);
                float v3 = __shfl(acc[r], sl3, 64);
                if (r == gg) { gi = v0; gf = v1; gc = v2; go = v3; }
            }
            gi = sigf(gi + bi);
            gf = sigf(gf + bf_);
            gc = tanh_f(gc + bg);
            go = sigf(go + bo);
            c = gf * c + gi * gc;
            h = go * tanh_f(c);

            // ---- coalesced h store: pack 4 cols of row myb into one u64 ----
            u32 w0 = f2b_rne(h);
            u32 w1 = (u32)__shfl((int)w0, baseln + 1, 64);
            u32 w2 = (u32)__shfl((int)w0, baseln + 2, 64);
            u32 w3 = (u32)__shfl((int)w0, baseln + 3, 64);
            if (jj == 0) {
                u64 pkd = (u64)(w0 | (w1 << 16)) | ((u64)(w2 | (w3 << 16)) << 32);
                u64* hw = (u64*)((LAYER == 0 ? h0base : h1base)
                                 + (size_t)((t + 1) & 1) * S_ELEMS)
                          + (size_t)bidL * 64 + myb;
                __hip_atomic_store(hw, pkd, __ATOMIC_RELAXED, __HIP_MEMORY_SCOPE_AGENT);
            }
        }
        // ---- arrival: drain h store, then ONE relaxed fetch-add ----
        if (i < TT) {
            asm volatile("s_waitcnt vmcnt(0)" ::: "memory");
            __syncthreads();   // all waves of this block drained
            if (tid == 0) add_u32_sc(mycnt, 1u);
        }
        // ---- shadow work while adds propagate / peers finish ----
        if (active) {
            if (LAYER == 1) {
                // packed out store: lane jj=0 writes float4 (cols bidL*4..+3)
                float o1 = __shfl(h, baseln + 1, 64);
                float o2 = __shfl(h, baseln + 2, 64);
                float o3 = __shfl(h, baseln + 3, 64);
                if (jj == 0) {
                    float4 ov = { h, o1, o2, o3 };
                    *(float4*)(out + (size_t)t * S_ELEMS + (size_t)myb * HH + bidL * 4) = ov;
                }
            }
            if (t == TT - 1) {
                float* fin = out + Y_ELEMS + (LAYER == 0 ? 0 : 2) * S_ELEMS;
                fin[myb * HH + col] = h;
                fin[S_ELEMS + myb * HH + col] = c;
            }
        }
        if (LAYER == 0 && i + 1 < TT) {      // prefetch x[t+1] into registers
            const float* xp = x + ((size_t)(i + 1) * BB + b0 + r16) * CC + q8;
            #pragma unroll
            for (int kt = 0; kt < 8; ++kt) {
                xf0[kt] = *(const float4*)(xp + kt * 32);
                xf1[kt] = *(const float4*)(xp + kt * 32 + 4);
            }
        }
        // ---- completion: tid0 polls the 8 counter lines (8 loads in flight) ----
        if (i < TT) {
            const u32 tgt = (u32)(i + 1) * 32u;   // 32 blocks per counter line
            if (tid == 0) {
                while (true) {
                    u32 v0 = ld_u32_sc(cnt + 0 * 32);
                    u32 v1 = ld_u32_sc(cnt + 1 * 32);
                    u32 v2 = ld_u32_sc(cnt + 2 * 32);
                    u32 v3 = ld_u32_sc(cnt + 3 * 32);
                    u32 v4 = ld_u32_sc(cnt + 4 * 32);
                    u32 v5 = ld_u32_sc(cnt + 5 * 32);
                    u32 v6 = ld_u32_sc(cnt + 6 * 32);
                    u32 v7 = ld_u32_sc(cnt + 7 * 32);
                    u32 m = min(min(min(v0, v1), min(v2, v3)),
                                min(min(v4, v5), min(v6, v7)));
                    if (m >= tgt) break;
                }
            }
            __syncthreads();
        }
    }
}

__global__ __launch_bounds__(256) __attribute__((amdgpu_waves_per_eu(1, 1)))
void k_lstm(const float* __restrict__ x,
            const float* __restrict__ c00,
            const float* __restrict__ c01,
            float* __restrict__ out,
            unsigned char* __restrict__ ws) {
    const int bid = blockIdx.x;
    if (bid < 128) run_ticks<0>(x, c00, out, ws, bid);
    else           run_ticks<1>(x, c01, out, ws, bid - 128);
}

extern "C" void kernel_launch(void* const* d_in, const int* in_sizes, int n_in,
                              void* d_out, int out_size, void* d_ws, size_t ws_size,
                              hipStream_t stream) {
    const float* x    = (const float*)d_in[0];
    const float* h0_0 = (const float*)d_in[1];
    const float* c0_0 = (const float*)d_in[2];
    const float* h0_1 = (const float*)d_in[3];
    const float* c0_1 = (const float*)d_in[4];
    const float* Wih0 = (const float*)d_in[5];
    const float* Whh0 = (const float*)d_in[6];
    const float* bih0 = (const float*)d_in[7];
    const float* bhh0 = (const float*)d_in[8];
    const float* Wih1 = (const float*)d_in[9];
    const float* Whh1 = (const float*)d_in[10];
    const float* bih1 = (const float*)d_in[11];
    const float* bhh1 = (const float*)d_in[12];
    float* out = (float*)d_out;
    unsigned char* ws = (unsigned char*)d_ws;

    k_init<<<128, 256, 0, stream>>>(bih0, bhh0, bih1, bhh1, h0_0, h0_1, ws);
    k_wprep<<<1792, 256, 0, stream>>>(Wih0, Whh0, Wih1, Whh1, ws);
    k_lstm<<<256, 256, 0, stream>>>(x, c0_0, c0_1, out, ws);
}

// Round 14
// 4717.130 us; speedup vs baseline: 1.1710x; 1.0566x over previous
//
#include <hip/hip_runtime.h>

// ---------------------------------------------------------------------------
// Persistent weight-stationary LSTM, bf16 MFMA, shared-A fat-M blocks.
// T=1024 B=64 C=256 H=512, 2 layers, fp32 in/out.
//  - 256 blocks x 256 threads, 1 block/CU; blocks 0..127 = layer0 (step t),
//    128..255 = layer1 (step t-1). Counter-join barrier (R13, best measured).
//  - NEW decomposition: block = 16 batches (bg of 4) x 16 cols (cg of 32).
//    All 4 waves consume the SAME 16 h rows -> block stages them ONCE into
//    LDS (16/32 KB, XOR-swizzled), waves ds_read A-frags. Per-wave compute
//    shape unchanged (M=16,N=16, NKT W-frags in VGPRs, same epilogue).
//    Global h traffic: 24 MB/tick -> 6 MB/tick (the ~6K-cy unexplained term:
//    LLC-stream + queueing; R8 proved the 4x cut but drowned it in W-LDS
//    broadcast + 4x epilogue costs -- this design has neither).
//  - h layout [colgroup cg][batch b][16 cols] u16: producer block writes its
//    512B slab via LDS-merge -> 32x16B contiguous full-line stores (R11 fix);
//    consumer staging reads 512B chunks coalesced.
//  - LDS swizzle: logical row-low ^= (m&7)<<4 -> stride-1024 frag reads are
//    2-way (free, m136). Staging ds_writes apply same XOR.
//  - mfma_f32_16x16x32_bf16: A[m=lane&15][k=quad*8+j], B(N,K)[n=lane&15][k=quad*8+j],
//    D[m=quad*4+reg][n=lane&15]  (guide-verified mapping, m90/m97 convention)
// ---------------------------------------------------------------------------

#define TT 1024
#define BB 64
#define CC 256
#define HH 512
#define Y_ELEMS (TT * BB * HH)
#define S_ELEMS (BB * HH)

typedef __attribute__((ext_vector_type(8))) short bf16x8;
typedef __attribute__((ext_vector_type(4))) float f32x4;
typedef unsigned int u32;
typedef unsigned short u16;
typedef unsigned long long u64;

// ---- ws layout (bytes) ----
#define WS_BAR 0           // (legacy, unused)
#define WS_CNT 32768       // 8 counter lines * 128B
#define WS_BSUM0 36864     // 2048 f32
#define WS_BSUM1 45056     // 2048 f32
#define WS_H0 53248        // 2 * 65536 B  (h0 ping-pong, [32cg][64b][16c] u16)
#define WS_H1 184320       // 2 * 65536 B  (h1 ping-pong, same layout)
#define WS_WPK0 315392     // 128*24*64*8 bf16  (layer0 packed W)
#define WS_WPK1 3461120    // 128*32*64*8 bf16  (layer1 packed W)
// end 7655424 (~7.66 MB)

__device__ __forceinline__ u16 f2b_rne(float f) {
    u32 u = __float_as_uint(f);
    return (u16)((u + 0x7FFFu + ((u >> 16) & 1u)) >> 16);
}
__device__ __forceinline__ u16 f2b_fast(float f) {  // round-half-up, 2 ops
    return (u16)((__float_as_uint(f) + 0x8000u) >> 16);
}
__device__ __forceinline__ float sigf(float z) { return 1.0f / (1.0f + __expf(-z)); }
__device__ __forceinline__ float tanh_f(float z) { return 2.0f / (1.0f + __expf(-2.0f * z)) - 1.0f; }

__device__ __forceinline__ bf16x8 pack8(float4 a, float4 b) {
    union { u16 u[8]; bf16x8 v; } r;
    r.u[0] = f2b_fast(a.x); r.u[1] = f2b_fast(a.y); r.u[2] = f2b_fast(a.z); r.u[3] = f2b_fast(a.w);
    r.u[4] = f2b_fast(b.x); r.u[5] = f2b_fast(b.y); r.u[6] = f2b_fast(b.z); r.u[7] = f2b_fast(b.w);
    return r.v;
}

__device__ __forceinline__ u32 ld_u32_sc(const u32* p) {
    return __hip_atomic_load(p, __ATOMIC_RELAXED, __HIP_MEMORY_SCOPE_AGENT);
}
__device__ __forceinline__ void add_u32_sc(u32* p, u32 v) {
    (void)__hip_atomic_fetch_add(p, v, __ATOMIC_RELAXED, __HIP_MEMORY_SCOPE_AGENT);
}

// ---- init: zero counters, bsum = bih+bhh, h slot0 <- bf16(h_init) ----
// layout: (b,col) -> u16 index (col>>4)*1024 + b*16 + (col&15)
__global__ void k_init(const float* __restrict__ bih0, const float* __restrict__ bhh0,
                       const float* __restrict__ bih1, const float* __restrict__ bhh1,
                       const float* __restrict__ h00, const float* __restrict__ h01,
                       unsigned char* __restrict__ ws) {
    u32* bar = (u32*)(ws + WS_BAR);
    float* bs0 = (float*)(ws + WS_BSUM0);
    float* bs1 = (float*)(ws + WS_BSUM1);
    u16* h0 = (u16*)(ws + WS_H0);
    u16* h1 = (u16*)(ws + WS_H1);
    int t = blockIdx.x * 256 + threadIdx.x;  // 32768 threads
    if (t < 8448) bar[t] = 0u;               // legacy flags + counter lines
    if (t < 2048) { bs0[t] = bih0[t] + bhh0[t]; bs1[t] = bih1[t] + bhh1[t]; }
    if (t < S_ELEMS) {
        int b = t >> 9, col = t & 511;
        int no = ((col >> 4) << 10) + (b << 4) + (col & 15);
        h0[no] = f2b_rne(h00[t]);
        h1[no] = f2b_rne(h01[t]);
    }
}

// ---- weight pack (UNCHANGED): tile v in [0,128) owns cols v*4..v*4+3 ----
__global__ void k_wprep(const float* __restrict__ Wih0, const float* __restrict__ Whh0,
                        const float* __restrict__ Wih1, const float* __restrict__ Whh1,
                        unsigned char* __restrict__ ws) {
    u16* wpk0 = (u16*)(ws + WS_WPK0);
    u16* wpk1 = (u16*)(ws + WS_WPK1);
    int u = blockIdx.x * 256 + threadIdx.x;  // 458752 threads
    const float* s;
    u16* d;
    if (u < 128 * 24 * 64) {  // layer0: 8 x-tiles (K=256) + 16 h-tiles (K=512)
        int bidL = u / (24 * 64);
        int kt = (u >> 6) % 24;
        int lane = u & 63;
        int n = lane & 15, quad = lane >> 4;
        int row = (n >> 2) * 512 + bidL * 4 + (n & 3);
        int k = kt * 32 + quad * 8;
        s = (k < 256) ? (Wih0 + (size_t)row * 256 + k) : (Whh0 + (size_t)row * 512 + (k - 256));
        d = wpk0 + (size_t)((bidL * 24 + kt) * 64 + lane) * 8;
    } else {  // layer1: 16 y0-tiles + 16 h1-tiles (K=1024)
        int v = u - 128 * 24 * 64;
        int bidL = v / (32 * 64);
        int kt = (v >> 6) % 32;
        int lane = v & 63;
        int n = lane & 15, quad = lane >> 4;
        int row = (n >> 2) * 512 + bidL * 4 + (n & 3);
        int k = kt * 32 + quad * 8;
        s = (k < 512) ? (Wih1 + (size_t)row * 512 + k) : (Whh1 + (size_t)row * 512 + (k - 512));
        d = wpk1 + (size_t)((bidL * 32 + kt) * 64 + lane) * 8;
    }
    #pragma unroll
    for (int i = 0; i < 8; ++i) d[i] = f2b_rne(s[i]);
}

// ---- the persistent tick loop, templated on layer ----
// lds: [0,32768) staged A rows (swizzled); [32768,33280) hstage (512 B)
template <int LAYER>
__device__ void run_ticks(const float* __restrict__ x, const float* __restrict__ c0,
                          float* __restrict__ out, unsigned char* __restrict__ ws,
                          int bidL, unsigned char* lds) {
    constexpr int NKT = (LAYER == 0) ? 24 : 32;
    constexpr int NL = (LAYER == 0) ? 4 : 8;      // staging 16B-loads per thread
    u32* cnt = (u32*)(ws + WS_CNT);               // 8 lines, stride 32 u32
    const float* bs = (const float*)(ws + (LAYER == 0 ? WS_BSUM0 : WS_BSUM1));
    u16* h0base = (u16*)(ws + WS_H0);
    u16* h1base = (u16*)(ws + WS_H1);
    const u16* wpk = (const u16*)(ws + (LAYER == 0 ? WS_WPK0 : WS_WPK1));

    const int bg = bidL >> 5;                 // batch group [0,4)
    const int cg = bidL & 31;                 // col group  [0,32)
    const int tid = threadIdx.x, lane = tid & 63, wave = tid >> 6;
    const int r16 = lane & 15, quad = lane >> 4, q8 = quad * 8;
    const int gg = r16 >> 2, jj = r16 & 3;
    const int col = cg * 16 + wave * 4 + jj;  // h column this lane finalizes
    const int mb = quad * 4 + gg;             // local batch this lane finalizes
    const int myb = bg * 16 + mb;             // global batch
    const int sl0 = (quad << 4) | (0 << 2) | jj;
    const int sl1 = (quad << 4) | (1 << 2) | jj;
    const int sl2 = (quad << 4) | (2 << 2) | jj;
    const int sl3 = (quad << 4) | (3 << 2) | jj;
    const int baseln = (quad << 4) | (gg << 2);   // lane jj=0 of my (quad,gg) group

    u16* hstage = (u16*)(lds + 32768);
    const int sw = (r16 & 7) << 4;            // frag-read XOR swizzle

    u32* mycnt = cnt + ((u32)blockIdx.x & 7) * 32;

    // biases (hoisted), c state in register for the whole run
    const float bi = bs[0 * HH + col], bf_ = bs[1 * HH + col];
    const float bg_ = bs[2 * HH + col], bo = bs[3 * HH + col];
    float c = c0[myb * HH + col];

    // weight fragments: tile v = cg*4 + wave (wpk layout unchanged)
    f32x4 wf[NKT];
    {
        const u16* wp = wpk + (size_t)((cg * 4 + wave) * NKT * 64 + lane) * 8;
        #pragma unroll
        for (int kt = 0; kt < NKT; ++kt) wf[kt] = *(const f32x4*)(wp + (size_t)kt * 64 * 8);
        #pragma unroll
        for (int kt = 0; kt < NKT; ++kt) asm volatile("" : "+v"(wf[kt]));
    }

    // layer0: x prefetch registers (t=0 issued before the loop); rows bg*16+r16
    float4 xf0[8], xf1[8];
    if (LAYER == 0) {
        const float* xp = x + (size_t)(bg * 16 + r16) * CC + q8;
        #pragma unroll
        for (int kt = 0; kt < 8; ++kt) {
            xf0[kt] = *(const float4*)(xp + kt * 32);
            xf1[kt] = *(const float4*)(xp + kt * 32 + 4);
        }
    }

    for (int i = 0; i <= TT; ++i) {
        const bool active = (LAYER == 0) ? (i < TT) : (i >= 1);
        const int t = (LAYER == 0) ? i : i - 1;
        float h = 0.f;
        if (active) {
            // ---- cooperative staging: h rows (this block's 16 batches) -> LDS ----
            f32x4 stg[NL];
            {
                const char* srcA = (const char*)(h0base + (size_t)((LAYER == 0 ? t : t + 1) & 1) * S_ELEMS);
                const char* srcB = (const char*)(h1base + (size_t)(t & 1) * S_ELEMS);
                #pragma unroll
                for (int k = 0; k < NL; ++k) {
                    int g = (k & 3) * 4096 + tid * 16;      // linear staging byte
                    int cgi = g >> 9;                        // chunk [0,32)
                    int off = g & 511;                       // within 512B chunk
                    const char* sp = ((LAYER == 1 && k >= 4) ? srcB : srcA)
                                   + (size_t)cgi * 2048 + bg * 512 + off;
                    asm volatile("global_load_dwordx4 %0, %1, off sc0 sc1"
                                 : "=&v"(stg[k]) : "v"(sp) : "memory");
                }
            }
            f32x4 a0 = {0.f,0.f,0.f,0.f}, a1 = {0.f,0.f,0.f,0.f};
            f32x4 a2 = {0.f,0.f,0.f,0.f}, a3 = {0.f,0.f,0.f,0.f};
            if (LAYER == 0) {
                // x projection (registers) overlaps the staging-load flight
                #pragma unroll
                for (int kt = 0; kt < 8; ++kt) {
                    bf16x8 a = pack8(xf0[kt], xf1[kt]);
                    bf16x8 wv = __builtin_bit_cast(bf16x8, wf[kt]);
                    f32x4& dst = (kt & 2) ? ((kt & 1) ? a3 : a2) : ((kt & 1) ? a1 : a0);
                    dst = __builtin_amdgcn_mfma_f32_16x16x32_bf16(a, wv, dst, 0, 0, 0);
                }
            }
            asm volatile("s_waitcnt vmcnt(0)" ::: "memory");
            // swizzled LDS writes: row m = off>>5, logical low = cgi*32+(off&16)
            #pragma unroll
            for (int k = 0; k < NL; ++k) {
                int g = (k & 3) * 4096 + tid * 16;
                int cgi = g >> 9;
                int off = g & 511;
                int m = off >> 5;
                int lo = (cgi * 32 + (off & 16)) ^ ((m & 7) << 4);
                int base = (LAYER == 1 && k >= 4) ? 16384 : 0;
                *(f32x4*)(lds + base + m * 1024 + lo) = stg[k];
            }
            __syncthreads();
            // ---- MFMA: A from LDS (swizzled), W from VGPR ----
            if (LAYER == 0) {
                #pragma unroll
                for (int kc = 0; kc < 16; kc += 8) {
                    bf16x8 av[8];
                    #pragma unroll
                    for (int j = 0; j < 8; ++j) {
                        int kt = kc + j;
                        int lo2 = (kt * 64 + quad * 16) ^ sw;
                        av[j] = *(const bf16x8*)(lds + r16 * 1024 + lo2);
                    }
                    #pragma unroll
                    for (int j = 0; j < 8; ++j) {
                        int kt = kc + j;
                        bf16x8 wv = __builtin_bit_cast(bf16x8, wf[8 + kt]);
                        f32x4& dst = (kt & 2) ? ((kt & 1) ? a3 : a2) : ((kt & 1) ? a1 : a0);
                        dst = __builtin_amdgcn_mfma_f32_16x16x32_bf16(av[j], wv, dst, 0, 0, 0);
                    }
                }
            } else {
                #pragma unroll
                for (int kc = 0; kc < 32; kc += 8) {
                    bf16x8 av[8];
                    #pragma unroll
                    for (int j = 0; j < 8; ++j) {
                        int kt = kc + j;
                        int base = (kt < 16) ? 0 : 16384;
                        int lo2 = ((kt & 15) * 64 + quad * 16) ^ sw;
                        av[j] = *(const bf16x8*)(lds + base + r16 * 1024 + lo2);
                    }
                    #pragma unroll
                    for (int j = 0; j < 8; ++j) {
                        int kt = kc + j;
                        bf16x8 wv = __builtin_bit_cast(bf16x8, wf[kt]);
                        f32x4& dst = (kt & 2) ? ((kt & 1) ? a3 : a2) : ((kt & 1) ? a1 : a0);
                        dst = __builtin_amdgcn_mfma_f32_16x16x32_bf16(av[j], wv, dst, 0, 0, 0);
                    }
                }
            }
            f32x4 acc = (a0 + a1) + (a2 + a3);

            // gates for (myb, col): lanes sharing (quad,jj), gg = gate
            float gi = 0.f, gf = 0.f, gc = 0.f, go = 0.f;
            #pragma unroll
            for (int r = 0; r < 4; ++r) {
                float v0 = __shfl(acc[r], sl0, 64);
                float v1 = __shfl(acc[r], sl1, 64);
                float v2 = __shfl(acc[r], sl2, 64);
                float v3 = __shfl(acc[r], sl3, 64);
                if (r == gg) { gi = v0; gf = v1; gc = v2; go = v3; }
            }
            gi = sigf(gi + bi);
            gf = sigf(gf + bf_);
            gc = tanh_f(gc + bg_);
            go = sigf(go + bo);
            c = gf * c + gi * gc;
            h = go * tanh_f(c);

            // ---- pack 4 cols into u64, merge in LDS (full-line store path) ----
            u32 w0 = f2b_rne(h);
            u32 w1 = (u32)__shfl((int)w0, baseln + 1, 64);
            u32 w2 = (u32)__shfl((int)w0, baseln + 2, 64);
            u32 w3 = (u32)__shfl((int)w0, baseln + 3, 64);
            if (jj == 0) {
                u64 pkd = (u64)(w0 | (w1 << 16)) | ((u64)(w2 | (w3 << 16)) << 32);
                *(u64*)((char*)hstage + mb * 32 + wave * 8) = pkd;
            }
        }
        // ---- arrival: LDS-merge -> 32x16B contiguous stores -> drain -> add ----
        if (i < TT) {
            __syncthreads();   // hstage complete; also aligns inactive edge ticks
            if (active && tid < 32) {
                u16* hw = (LAYER == 0 ? h0base : h1base) + (size_t)((t + 1) & 1) * S_ELEMS;
                f32x4 v = *(const f32x4*)((const char*)hstage + tid * 16);
                const char* dp = (const char*)hw + (size_t)cg * 2048 + bg * 512 + tid * 16;
                asm volatile("global_store_dwordx4 %0, %1, off sc0 sc1"
                             :: "v"(dp), "v"(v) : "memory");
            }
            asm volatile("s_waitcnt vmcnt(0)" ::: "memory");
            __syncthreads();
            if (tid == 0) add_u32_sc(mycnt, 1u);
        }
        // ---- shadow work while adds propagate / peers finish ----
        if (active) {
            if (LAYER == 1) {
                float o1 = __shfl(h, baseln + 1, 64);
                float o2 = __shfl(h, baseln + 2, 64);
                float o3 = __shfl(h, baseln + 3, 64);
                if (jj == 0) {
                    float4 ov = { h, o1, o2, o3 };
                    *(float4*)(out + (size_t)t * S_ELEMS + (size_t)myb * HH
                               + cg * 16 + wave * 4) = ov;
                }
            }
            if (t == TT - 1) {
                float* fin = out + Y_ELEMS + (LAYER == 0 ? 0 : 2) * S_ELEMS;
                fin[myb * HH + col] = h;
                fin[S_ELEMS + myb * HH + col] = c;
            }
        }
        if (LAYER == 0 && i + 1 < TT) {      // prefetch x[t+1] into registers
            const float* xp = x + ((size_t)(i + 1) * BB + bg * 16 + r16) * CC + q8;
            #pragma unroll
            for (int kt = 0; kt < 8; ++kt) {
                xf0[kt] = *(const float4*)(xp + kt * 32);
                xf1[kt] = *(const float4*)(xp + kt * 32 + 4);
            }
        }
        // ---- completion: tid0 polls the 8 counter lines (R13) ----
        if (i < TT) {
            const u32 tgt = (u32)(i + 1) * 32u;   // 32 blocks per counter line
            if (tid == 0) {
                while (true) {
                    u32 v0 = ld_u32_sc(cnt + 0 * 32);
                    u32 v1 = ld_u32_sc(cnt + 1 * 32);
                    u32 v2 = ld_u32_sc(cnt + 2 * 32);
                    u32 v3 = ld_u32_sc(cnt + 3 * 32);
                    u32 v4 = ld_u32_sc(cnt + 4 * 32);
                    u32 v5 = ld_u32_sc(cnt + 5 * 32);
                    u32 v6 = ld_u32_sc(cnt + 6 * 32);
                    u32 v7 = ld_u32_sc(cnt + 7 * 32);
                    u32 m = min(min(min(v0, v1), min(v2, v3)),
                                min(min(v4, v5), min(v6, v7)));
                    if (m >= tgt) break;
                }
            }
            __syncthreads();
        }
    }
}

__global__ __launch_bounds__(256) __attribute__((amdgpu_waves_per_eu(1, 1)))
void k_lstm(const float* __restrict__ x,
            const float* __restrict__ c00,
            const float* __restrict__ c01,
            float* __restrict__ out,
            unsigned char* __restrict__ ws) {
    __shared__ __align__(16) unsigned char lds[33280];  // 32KB A-stage + 512B hstage
    const int bid = blockIdx.x;
    if (bid < 128) run_ticks<0>(x, c00, out, ws, bid, lds);
    else           run_ticks<1>(x, c01, out, ws, bid - 128, lds);
}

extern "C" void kernel_launch(void* const* d_in, const int* in_sizes, int n_in,
                              void* d_out, int out_size, void* d_ws, size_t ws_size,
                              hipStream_t stream) {
    const float* x    = (const float*)d_in[0];
    const float* h0_0 = (const float*)d_in[1];
    const float* c0_0 = (const float*)d_in[2];
    const float* h0_1 = (const float*)d_in[3];
    const float* c0_1 = (const float*)d_in[4];
    const float* Wih0 = (const float*)d_in[5];
    const float* Whh0 = (const float*)d_in[6];
    const float* bih0 = (const float*)d_in[7];
    const float* bhh0 = (const float*)d_in[8];
    const float* Wih1 = (const float*)d_in[9];
    const float* Whh1 = (const float*)d_in[10];
    const float* bih1 = (const float*)d_in[11];
    const float* bhh1 = (const float*)d_in[12];
    float* out = (float*)d_out;
    unsigned char* ws = (unsigned char*)d_ws;

    k_init<<<128, 256, 0, stream>>>(bih0, bhh0, bih1, bhh1, h0_0, h0_1, ws);
    k_wprep<<<1792, 256, 0, stream>>>(Wih0, Whh0, Wih1, Whh1, ws);
    k_lstm<<<256, 256, 0, stream>>>(x, c0_0, c0_1, out, ws);
}

// Round 15
// 4572.766 us; speedup vs baseline: 1.2080x; 1.0316x over previous
//
#include <hip/hip_runtime.h>

// ---------------------------------------------------------------------------
// Persistent weight-stationary LSTM, bf16 MFMA, shared-A blocks, PER-GROUP sync.
// T=1024 B=64 C=256 H=512, 2 layers, fp32 in/out.
//  - 256 blocks x 256 threads, 1 block/CU; blocks 0..127 = layer0 (step t),
//    128..255 = layer1 (step t-1). Block = (layer, bg, cg): 16 batches
//    (bg of 4) x 16 cols (cg of 32); 4 waves share staged A rows (R14).
//  - KEY CHANGE vs R14: the barrier is PER BATCH-GROUP. R14's dataflow is
//    already batch-partitioned (block touches only bg's h/x/out slabs); the
//    global 256-block join was the only coupling. Now group bg = 64 blocks
//    (32 L0 + 32 L1) with its own 4 counter lines (16 blocks each); poll own
//    group's lines for 16*(i+1). Tick period = max over 64 blocks (not 256);
//    groups drift out of phase -> staging bursts de-synchronize (6 MB global
//    burst -> staggered ~1.5 MB bursts), shorter LLC queueing per round.
//  - Everything else byte-identical to R14: LDS A-staging (XOR-swizzled),
//    [cg][b][16c] u64 h layout w/ LDS-merged full-line stores, W in VGPRs,
//    counter-join arithmetic, float4 out, x reg-prefetch.
//  - mfma_f32_16x16x32_bf16: A[m=lane&15][k=quad*8+j], B(N,K)[n=lane&15][k=quad*8+j],
//    D[m=quad*4+reg][n=lane&15]  (guide-verified mapping, m90/m97 convention)
// ---------------------------------------------------------------------------

#define TT 1024
#define BB 64
#define CC 256
#define HH 512
#define Y_ELEMS (TT * BB * HH)
#define S_ELEMS (BB * HH)

typedef __attribute__((ext_vector_type(8))) short bf16x8;
typedef __attribute__((ext_vector_type(4))) float f32x4;
typedef unsigned int u32;
typedef unsigned short u16;
typedef unsigned long long u64;

// ---- ws layout (bytes) ----
#define WS_BAR 0           // (legacy, unused)
#define WS_CNT 32768       // 16 counter lines * 128B (4 per batch-group)
#define WS_BSUM0 36864     // 2048 f32
#define WS_BSUM1 45056     // 2048 f32
#define WS_H0 53248        // 2 * 65536 B  (h0 ping-pong, [32cg][64b][16c] u16)
#define WS_H1 184320       // 2 * 65536 B  (h1 ping-pong, same layout)
#define WS_WPK0 315392     // 128*24*64*8 bf16  (layer0 packed W)
#define WS_WPK1 3461120    // 128*32*64*8 bf16  (layer1 packed W)
// end 7655424 (~7.66 MB)

__device__ __forceinline__ u16 f2b_rne(float f) {
    u32 u = __float_as_uint(f);
    return (u16)((u + 0x7FFFu + ((u >> 16) & 1u)) >> 16);
}
__device__ __forceinline__ u16 f2b_fast(float f) {  // round-half-up, 2 ops
    return (u16)((__float_as_uint(f) + 0x8000u) >> 16);
}
__device__ __forceinline__ float sigf(float z) { return 1.0f / (1.0f + __expf(-z)); }
__device__ __forceinline__ float tanh_f(float z) { return 2.0f / (1.0f + __expf(-2.0f * z)) - 1.0f; }

__device__ __forceinline__ bf16x8 pack8(float4 a, float4 b) {
    union { u16 u[8]; bf16x8 v; } r;
    r.u[0] = f2b_fast(a.x); r.u[1] = f2b_fast(a.y); r.u[2] = f2b_fast(a.z); r.u[3] = f2b_fast(a.w);
    r.u[4] = f2b_fast(b.x); r.u[5] = f2b_fast(b.y); r.u[6] = f2b_fast(b.z); r.u[7] = f2b_fast(b.w);
    return r.v;
}

__device__ __forceinline__ u32 ld_u32_sc(const u32* p) {
    return __hip_atomic_load(p, __ATOMIC_RELAXED, __HIP_MEMORY_SCOPE_AGENT);
}
__device__ __forceinline__ void add_u32_sc(u32* p, u32 v) {
    (void)__hip_atomic_fetch_add(p, v, __ATOMIC_RELAXED, __HIP_MEMORY_SCOPE_AGENT);
}

// ---- init: zero counters, bsum = bih+bhh, h slot0 <- bf16(h_init) ----
// layout: (b,col) -> u16 index (col>>4)*1024 + b*16 + (col&15)
__global__ void k_init(const float* __restrict__ bih0, const float* __restrict__ bhh0,
                       const float* __restrict__ bih1, const float* __restrict__ bhh1,
                       const float* __restrict__ h00, const float* __restrict__ h01,
                       unsigned char* __restrict__ ws) {
    u32* bar = (u32*)(ws + WS_BAR);
    float* bs0 = (float*)(ws + WS_BSUM0);
    float* bs1 = (float*)(ws + WS_BSUM1);
    u16* h0 = (u16*)(ws + WS_H0);
    u16* h1 = (u16*)(ws + WS_H1);
    int t = blockIdx.x * 256 + threadIdx.x;  // 32768 threads
    if (t < 8704) bar[t] = 0u;               // legacy flags + 16 counter lines
    if (t < 2048) { bs0[t] = bih0[t] + bhh0[t]; bs1[t] = bih1[t] + bhh1[t]; }
    if (t < S_ELEMS) {
        int b = t >> 9, col = t & 511;
        int no = ((col >> 4) << 10) + (b << 4) + (col & 15);
        h0[no] = f2b_rne(h00[t]);
        h1[no] = f2b_rne(h01[t]);
    }
}

// ---- weight pack (UNCHANGED): tile v in [0,128) owns cols v*4..v*4+3 ----
__global__ void k_wprep(const float* __restrict__ Wih0, const float* __restrict__ Whh0,
                        const float* __restrict__ Wih1, const float* __restrict__ Whh1,
                        unsigned char* __restrict__ ws) {
    u16* wpk0 = (u16*)(ws + WS_WPK0);
    u16* wpk1 = (u16*)(ws + WS_WPK1);
    int u = blockIdx.x * 256 + threadIdx.x;  // 458752 threads
    const float* s;
    u16* d;
    if (u < 128 * 24 * 64) {  // layer0: 8 x-tiles (K=256) + 16 h-tiles (K=512)
        int bidL = u / (24 * 64);
        int kt = (u >> 6) % 24;
        int lane = u & 63;
        int n = lane & 15, quad = lane >> 4;
        int row = (n >> 2) * 512 + bidL * 4 + (n & 3);
        int k = kt * 32 + quad * 8;
        s = (k < 256) ? (Wih0 + (size_t)row * 256 + k) : (Whh0 + (size_t)row * 512 + (k - 256));
        d = wpk0 + (size_t)((bidL * 24 + kt) * 64 + lane) * 8;
    } else {  // layer1: 16 y0-tiles + 16 h1-tiles (K=1024)
        int v = u - 128 * 24 * 64;
        int bidL = v / (32 * 64);
        int kt = (v >> 6) % 32;
        int lane = v & 63;
        int n = lane & 15, quad = lane >> 4;
        int row = (n >> 2) * 512 + bidL * 4 + (n & 3);
        int k = kt * 32 + quad * 8;
        s = (k < 512) ? (Wih1 + (size_t)row * 512 + k) : (Whh1 + (size_t)row * 512 + (k - 512));
        d = wpk1 + (size_t)((bidL * 32 + kt) * 64 + lane) * 8;
    }
    #pragma unroll
    for (int i = 0; i < 8; ++i) d[i] = f2b_rne(s[i]);
}

// ---- the persistent tick loop, templated on layer ----
// lds: [0,32768) staged A rows (swizzled); [32768,33280) hstage (512 B)
template <int LAYER>
__device__ void run_ticks(const float* __restrict__ x, const float* __restrict__ c0,
                          float* __restrict__ out, unsigned char* __restrict__ ws,
                          int bidL, unsigned char* lds) {
    constexpr int NKT = (LAYER == 0) ? 24 : 32;
    constexpr int NL = (LAYER == 0) ? 4 : 8;      // staging 16B-loads per thread
    u32* cnt = (u32*)(ws + WS_CNT);               // 16 lines, stride 32 u32
    const float* bs = (const float*)(ws + (LAYER == 0 ? WS_BSUM0 : WS_BSUM1));
    u16* h0base = (u16*)(ws + WS_H0);
    u16* h1base = (u16*)(ws + WS_H1);
    const u16* wpk = (const u16*)(ws + (LAYER == 0 ? WS_WPK0 : WS_WPK1));

    const int bg = bidL >> 5;                 // batch group [0,4) -- sync group
    const int cg = bidL & 31;                 // col group  [0,32)
    const int tid = threadIdx.x, lane = tid & 63, wave = tid >> 6;
    const int r16 = lane & 15, quad = lane >> 4, q8 = quad * 8;
    const int gg = r16 >> 2, jj = r16 & 3;
    const int col = cg * 16 + wave * 4 + jj;  // h column this lane finalizes
    const int mb = quad * 4 + gg;             // local batch this lane finalizes
    const int myb = bg * 16 + mb;             // global batch
    const int sl0 = (quad << 4) | (0 << 2) | jj;
    const int sl1 = (quad << 4) | (1 << 2) | jj;
    const int sl2 = (quad << 4) | (2 << 2) | jj;
    const int sl3 = (quad << 4) | (3 << 2) | jj;
    const int baseln = (quad << 4) | (gg << 2);   // lane jj=0 of my (quad,gg) group

    u16* hstage = (u16*)(lds + 32768);
    const int sw = (r16 & 7) << 4;            // frag-read XOR swizzle

    // per-group barrier: group bg's 4 lines; 16 blocks arrive per line
    u32* gcnt = cnt + (u32)bg * 4 * 32;
    u32* mycnt = gcnt + (u32)((LAYER * 32 + cg) & 3) * 32;

    // biases (hoisted), c state in register for the whole run
    const float bi = bs[0 * HH + col], bf_ = bs[1 * HH + col];
    const float bg_ = bs[2 * HH + col], bo = bs[3 * HH + col];
    float c = c0[myb * HH + col];

    // weight fragments: tile v = cg*4 + wave (wpk layout unchanged)
    f32x4 wf[NKT];
    {
        const u16* wp = wpk + (size_t)((cg * 4 + wave) * NKT * 64 + lane) * 8;
        #pragma unroll
        for (int kt = 0; kt < NKT; ++kt) wf[kt] = *(const f32x4*)(wp + (size_t)kt * 64 * 8);
        #pragma unroll
        for (int kt = 0; kt < NKT; ++kt) asm volatile("" : "+v"(wf[kt]));
    }

    // layer0: x prefetch registers (t=0 issued before the loop); rows bg*16+r16
    float4 xf0[8], xf1[8];
    if (LAYER == 0) {
        const float* xp = x + (size_t)(bg * 16 + r16) * CC + q8;
        #pragma unroll
        for (int kt = 0; kt < 8; ++kt) {
            xf0[kt] = *(const float4*)(xp + kt * 32);
            xf1[kt] = *(const float4*)(xp + kt * 32 + 4);
        }
    }

    for (int i = 0; i <= TT; ++i) {
        const bool active = (LAYER == 0) ? (i < TT) : (i >= 1);
        const int t = (LAYER == 0) ? i : i - 1;
        float h = 0.f;
        if (active) {
            // ---- cooperative staging: h rows (this block's 16 batches) -> LDS ----
            f32x4 stg[NL];
            {
                const char* srcA = (const char*)(h0base + (size_t)((LAYER == 0 ? t : t + 1) & 1) * S_ELEMS);
                const char* srcB = (const char*)(h1base + (size_t)(t & 1) * S_ELEMS);
                #pragma unroll
                for (int k = 0; k < NL; ++k) {
                    int g = (k & 3) * 4096 + tid * 16;      // linear staging byte
                    int cgi = g >> 9;                        // chunk [0,32)
                    int off = g & 511;                       // within 512B chunk
                    const char* sp = ((LAYER == 1 && k >= 4) ? srcB : srcA)
                                   + (size_t)cgi * 2048 + bg * 512 + off;
                    asm volatile("global_load_dwordx4 %0, %1, off sc0 sc1"
                                 : "=&v"(stg[k]) : "v"(sp) : "memory");
                }
            }
            f32x4 a0 = {0.f,0.f,0.f,0.f}, a1 = {0.f,0.f,0.f,0.f};
            f32x4 a2 = {0.f,0.f,0.f,0.f}, a3 = {0.f,0.f,0.f,0.f};
            if (LAYER == 0) {
                // x projection (registers) overlaps the staging-load flight
                #pragma unroll
                for (int kt = 0; kt < 8; ++kt) {
                    bf16x8 a = pack8(xf0[kt], xf1[kt]);
                    bf16x8 wv = __builtin_bit_cast(bf16x8, wf[kt]);
                    f32x4& dst = (kt & 2) ? ((kt & 1) ? a3 : a2) : ((kt & 1) ? a1 : a0);
                    dst = __builtin_amdgcn_mfma_f32_16x16x32_bf16(a, wv, dst, 0, 0, 0);
                }
            }
            asm volatile("s_waitcnt vmcnt(0)" ::: "memory");
            // swizzled LDS writes: row m = off>>5, logical low = cgi*32+(off&16)
            #pragma unroll
            for (int k = 0; k < NL; ++k) {
                int g = (k & 3) * 4096 + tid * 16;
                int cgi = g >> 9;
                int off = g & 511;
                int m = off >> 5;
                int lo = (cgi * 32 + (off & 16)) ^ ((m & 7) << 4);
                int base = (LAYER == 1 && k >= 4) ? 16384 : 0;
                *(f32x4*)(lds + base + m * 1024 + lo) = stg[k];
            }
            __syncthreads();
            // ---- MFMA: A from LDS (swizzled), W from VGPR ----
            if (LAYER == 0) {
                #pragma unroll
                for (int kc = 0; kc < 16; kc += 8) {
                    bf16x8 av[8];
                    #pragma unroll
                    for (int j = 0; j < 8; ++j) {
                        int kt = kc + j;
                        int lo2 = (kt * 64 + quad * 16) ^ sw;
                        av[j] = *(const bf16x8*)(lds + r16 * 1024 + lo2);
                    }
                    #pragma unroll
                    for (int j = 0; j < 8; ++j) {
                        int kt = kc + j;
                        bf16x8 wv = __builtin_bit_cast(bf16x8, wf[8 + kt]);
                        f32x4& dst = (kt & 2) ? ((kt & 1) ? a3 : a2) : ((kt & 1) ? a1 : a0);
                        dst = __builtin_amdgcn_mfma_f32_16x16x32_bf16(av[j], wv, dst, 0, 0, 0);
                    }
                }
            } else {
                #pragma unroll
                for (int kc = 0; kc < 32; kc += 8) {
                    bf16x8 av[8];
                    #pragma unroll
                    for (int j = 0; j < 8; ++j) {
                        int kt = kc + j;
                        int base = (kt < 16) ? 0 : 16384;
                        int lo2 = ((kt & 15) * 64 + quad * 16) ^ sw;
                        av[j] = *(const bf16x8*)(lds + base + r16 * 1024 + lo2);
                    }
                    #pragma unroll
                    for (int j = 0; j < 8; ++j) {
                        int kt = kc + j;
                        bf16x8 wv = __builtin_bit_cast(bf16x8, wf[kt]);
                        f32x4& dst = (kt & 2) ? ((kt & 1) ? a3 : a2) : ((kt & 1) ? a1 : a0);
                        dst = __builtin_amdgcn_mfma_f32_16x16x32_bf16(av[j], wv, dst, 0, 0, 0);
                    }
                }
            }
            f32x4 acc = (a0 + a1) + (a2 + a3);

            // gates for (myb, col): lanes sharing (quad,jj), gg = gate
            float gi = 0.f, gf = 0.f, gc = 0.f, go = 0.f;
            #pragma unroll
            for (int r = 0; r < 4; ++r) {
                float v0 = __shfl(acc[r], sl0, 64);
                float v1 = __shfl(acc[r], sl1, 64);
                float v2 = __shfl(acc[r], sl2, 64);
                float v3 = __shfl(acc[r], sl3, 64);
                if (r == gg) { gi = v0; gf = v1; gc = v2; go = v3; }
            }
            gi = sigf(gi + bi);
            gf = sigf(gf + bf_);
            gc = tanh_f(gc + bg_);
            go = sigf(go + bo);
            c = gf * c + gi * gc;
            h = go * tanh_f(c);

            // ---- pack 4 cols into u64, merge in LDS (full-line store path) ----
            u32 w0 = f2b_rne(h);
            u32 w1 = (u32)__shfl((int)w0, baseln + 1, 64);
            u32 w2 = (u32)__shfl((int)w0, baseln + 2, 64);
            u32 w3 = (u32)__shfl((int)w0, baseln + 3, 64);
            if (jj == 0) {
                u64 pkd = (u64)(w0 | (w1 << 16)) | ((u64)(w2 | (w3 << 16)) << 32);
                *(u64*)((char*)hstage + mb * 32 + wave * 8) = pkd;
            }
        }
        // ---- arrival: LDS-merge -> 32x16B contiguous stores -> drain -> add ----
        if (i < TT) {
            __syncthreads();   // hstage complete; also aligns inactive edge ticks
            if (active && tid < 32) {
                u16* hw = (LAYER == 0 ? h0base : h1base) + (size_t)((t + 1) & 1) * S_ELEMS;
                f32x4 v = *(const f32x4*)((const char*)hstage + tid * 16);
                const char* dp = (const char*)hw + (size_t)cg * 2048 + bg * 512 + tid * 16;
                asm volatile("global_store_dwordx4 %0, %1, off sc0 sc1"
                             :: "v"(dp), "v"(v) : "memory");
            }
            asm volatile("s_waitcnt vmcnt(0)" ::: "memory");
            __syncthreads();
            if (tid == 0) add_u32_sc(mycnt, 1u);
        }
        // ---- shadow work while adds propagate / peers finish ----
        if (active) {
            if (LAYER == 1) {
                float o1 = __shfl(h, baseln + 1, 64);
                float o2 = __shfl(h, baseln + 2, 64);
                float o3 = __shfl(h, baseln + 3, 64);
                if (jj == 0) {
                    float4 ov = { h, o1, o2, o3 };
                    *(float4*)(out + (size_t)t * S_ELEMS + (size_t)myb * HH
                               + cg * 16 + wave * 4) = ov;
                }
            }
            if (t == TT - 1) {
                float* fin = out + Y_ELEMS + (LAYER == 0 ? 0 : 2) * S_ELEMS;
                fin[myb * HH + col] = h;
                fin[S_ELEMS + myb * HH + col] = c;
            }
        }
        if (LAYER == 0 && i + 1 < TT) {      // prefetch x[t+1] into registers
            const float* xp = x + ((size_t)(i + 1) * BB + bg * 16 + r16) * CC + q8;
            #pragma unroll
            for (int kt = 0; kt < 8; ++kt) {
                xf0[kt] = *(const float4*)(xp + kt * 32);
                xf1[kt] = *(const float4*)(xp + kt * 32 + 4);
            }
        }
        // ---- completion: tid0 polls OWN GROUP's 4 counter lines ----
        if (i < TT) {
            const u32 tgt = (u32)(i + 1) * 16u;   // 16 blocks per counter line
            if (tid == 0) {
                while (true) {
                    u32 v0 = ld_u32_sc(gcnt + 0 * 32);
                    u32 v1 = ld_u32_sc(gcnt + 1 * 32);
                    u32 v2 = ld_u32_sc(gcnt + 2 * 32);
                    u32 v3 = ld_u32_sc(gcnt + 3 * 32);
                    u32 m = min(min(v0, v1), min(v2, v3));
                    if (m >= tgt) break;
                }
            }
            __syncthreads();
        }
    }
}

__global__ __launch_bounds__(256) __attribute__((amdgpu_waves_per_eu(1, 1)))
void k_lstm(const float* __restrict__ x,
            const float* __restrict__ c00,
            const float* __restrict__ c01,
            float* __restrict__ out,
            unsigned char* __restrict__ ws) {
    __shared__ __align__(16) unsigned char lds[33280];  // 32KB A-stage + 512B hstage
    const int bid = blockIdx.x;
    if (bid < 128) run_ticks<0>(x, c00, out, ws, bid, lds);
    else           run_ticks<1>(x, c01, out, ws, bid - 128, lds);
}

extern "C" void kernel_launch(void* const* d_in, const int* in_sizes, int n_in,
                              void* d_out, int out_size, void* d_ws, size_t ws_size,
                              hipStream_t stream) {
    const float* x    = (const float*)d_in[0];
    const float* h0_0 = (const float*)d_in[1];
    const float* c0_0 = (const float*)d_in[2];
    const float* h0_1 = (const float*)d_in[3];
    const float* c0_1 = (const float*)d_in[4];
    const float* Wih0 = (const float*)d_in[5];
    const float* Whh0 = (const float*)d_in[6];
    const float* bih0 = (const float*)d_in[7];
    const float* bhh0 = (const float*)d_in[8];
    const float* Wih1 = (const float*)d_in[9];
    const float* Whh1 = (const float*)d_in[10];
    const float* bih1 = (const float*)d_in[11];
    const float* bhh1 = (const float*)d_in[12];
    float* out = (float*)d_out;
    unsigned char* ws = (unsigned char*)d_ws;

    k_init<<<128, 256, 0, stream>>>(bih0, bhh0, bih1, bhh1, h0_0, h0_1, ws);
    k_wprep<<<1792, 256, 0, stream>>>(Wih0, Whh0, Wih1, Whh1, ws);
    k_lstm<<<256, 256, 0, stream>>>(x, c0_0, c0_1, out, ws);
}